// Round 4
// baseline (2265.426 us; speedup 1.0000x reference)
//
#include <hip/hip_runtime.h>
#include <math.h>

typedef unsigned int u32;
typedef unsigned short u16;
typedef unsigned long long u64;

#define BATCH 64
#define A_TOT 8649
#define TOPN  6000
#define POST  1500
#define NB    4096
#define NT    512
#define NWAVE 8
#define NSLOT 12
#define NCHUNK 94          // ceil(6000/64): chunk s holds ranks [s*64, s*64+64)
#define HOR   12           // lazy horizon: consume only chunks <= torch+HOR
#define DONEBIT 0x80000000u
#define CNTMASK 0x7FFFFFFFu
#define GUARD_MAX (1 << 18)

// LDS layout (bytes); overlapping regions have disjoint lifetimes:
//   [0,      69192)  keys    u64[8649]   ([0,48000) live to the end: scores)
//   [69632,  86016)  bucketA u32[4096]   (sort only)
//   [86016, 102400)  bucketB u32[4096]   (sort only)
//   [102400,106496)  stemp   u32[1024]   (scan only)
//   [69632,  93632)  ring    float4[1500] (NMS; overlaps dead buckets)
//   [93632, 105632)  pp      u16[6000]    (NMS/epilogue; overlaps dead bucketB)
//   [105632,105652)  ctrl: u32 prodcnt, u32 torch, u32 bm[3] (overlaps dead stemp)
#define LDS_BYTES 106496

__global__ __launch_bounds__(NT, 2) void roibbox_kernel(
    const float* __restrict__ deltas,    // [B, A, 4]
    const float* __restrict__ probs,     // [B, A]
    const float* __restrict__ anchors,   // [A, 4]
    float* __restrict__ out)             // [B*POST*4] boxes then [B*POST] scores
{
    #pragma clang fp contract(off)
    __shared__ alignas(16) char smem[LDS_BYTES];
    u64*    keysL   = (u64*)   (smem + 0);
    u32*    bucketA = (u32*)   (smem + 69632);
    u32*    bucketB = (u32*)   (smem + 86016);
    u32*    stemp   = (u32*)   (smem + 102400);
    float4* ringL   = (float4*)(smem + 69632);
    u16*    ppL     = (u16*)   (smem + 93632);
    u32*    ctrlP   = (u32*)   (smem + 105632);   // produced count | DONEBIT
    u32*    ctrlF   = (u32*)   (smem + 105636);   // torch: frontier chunk index
    u32*    bmL     = (u32*)   (smem + 105640);   // [3] confirmed-dead chunk bitmap

    const int tid = threadIdx.x;
    const int b   = blockIdx.x;
    const u32 lane = (u32)tid & 63u;
    const u32 w    = (u32)tid >> 6;
    const float* pb = probs + (size_t)b * A_TOT;

    // ---------- init ----------
    #pragma unroll
    for (int i = 0; i < NB/NT; ++i) bucketA[tid + i*NT] = 0u;
    __syncthreads();

    // ---------- histogram (bucket by score; reversed so bucket 0 = highest) ----------
    for (int j = tid; j < A_TOT; j += NT) {
        float s = pb[j];
        int bkt = (int)(s * (float)NB);
        bkt = (NB-1) - min(max(bkt, 0), NB-1);
        atomicAdd(&bucketA[bkt], 1u);
    }
    __syncthreads();

    // ---------- exclusive scan over 4096 counts ----------
    {
        int base8 = tid << 3;
        u32 c[8]; u32 ms = 0;
        #pragma unroll
        for (int i = 0; i < 8; ++i) { c[i] = bucketA[base8+i]; ms += c[i]; }
        stemp[tid] = ms;
        __syncthreads();
        int src = 0;
        for (int off = 1; off < NT; off <<= 1) {
            u32 v = stemp[src*NT + tid];
            if (tid >= off) v += stemp[src*NT + tid - off];
            stemp[(src^1)*NT + tid] = v;
            __syncthreads();
            src ^= 1;
        }
        u32 excl = stemp[src*NT + tid] - ms;
        #pragma unroll
        for (int i = 0; i < 8; ++i) {
            bucketA[base8+i] = excl; bucketB[base8+i] = excl; excl += c[i];
        }
    }
    __syncthreads();

    // ---------- scatter keys into LDS ----------
    for (int j = tid; j < A_TOT; j += NT) {
        float s = pb[j];
        int bkt = (int)(s * (float)NB);
        bkt = (NB-1) - min(max(bkt, 0), NB-1);
        u32 pos = atomicAdd(&bucketB[bkt], 1u);
        keysL[pos] = ((u64)__float_as_uint(s) << 32) | (u64)(~(u32)j);
    }
    __syncthreads();

    // ---------- per-bucket insertion sort (descending; keys unique) ----------
    for (int bkt = tid; bkt < NB; bkt += NT) {
        int begin = (int)bucketA[bkt], end = (int)bucketB[bkt];
        for (int k = begin + 1; k < end; ++k) {
            u64 key = keysL[k];
            int m = k - 1;
            while (m >= begin && keysL[m] < key) { keysL[m+1] = keysL[m]; --m; }
            keysL[m+1] = key;
        }
    }
    __syncthreads();

    // ---------- decode, round-robin chunks: chunk s = i*8+w, rank = s*64+lane ----------
    float ry1[NSLOT], rx1[NSLOT], ry2[NSLOT], rx2[NSLOT], rA[NSLOT];
    u32 mask = 0;
    #pragma unroll
    for (int i = 0; i < NSLOT; ++i) {
        u32 s = (u32)i*8u + w;
        u32 r = s*64u + lane;
        ry1[i]=0.f; rx1[i]=0.f; ry2[i]=0.f; rx2[i]=0.f; rA[i]=0.f;
        if (s < NCHUNK && r < TOPN) {
            u64 k = keysL[r];
            u32 aidx = ~((u32)k);
            float4 av = *(const float4*)(anchors + (size_t)aidx * 4);
            float4 dv = *(const float4*)(deltas + ((size_t)b * A_TOT + aidx) * 4);
            float d0 = dv.x*0.1f, d1 = dv.y*0.1f, d2 = dv.z*0.2f, d3 = dv.w*0.2f;
            float ah = av.z - av.x, aw = av.w - av.y;
            float acy = av.x + 0.5f*ah, acx = av.y + 0.5f*aw;
            float h  = (float)exp((double)d2) * ah;   // correctly-rounded fp32 exp
            float wd = (float)exp((double)d3) * aw;
            float cy = d0*ah + acy;                   // contract(off): mul then add
            float cx = d1*aw + acx;
            ry1[i] = cy - 0.5f*h;  rx1[i] = cx - 0.5f*wd;
            ry2[i] = cy + 0.5f*h;  rx2[i] = cx + 0.5f*wd;
            rA[i]  = (ry2[i]-ry1[i])*(rx2[i]-rx1[i]);
            mask |= 1u << i;
        }
    }
    u32 slotAlive = 0;
    #pragma unroll
    for (int i = 0; i < NSLOT; ++i)
        if (__ballot((mask >> i) & 1u)) slotAlive |= 1u << i;

    u32 consS[NSLOT];
    #pragma unroll
    for (int i = 0; i < NSLOT; ++i) consS[i] = 0u;

    for (int j = tid; j < TOPN/2; j += NT) ((u32*)ppL)[j] = 0xFFFFFFFFu;
    if (tid == 0) { *ctrlP = 0u; *ctrlF = 0u; bmL[0] = 0u; bmL[1] = 0u; bmL[2] = 0xC0000000u; }
    __syncthreads();

    // suppress iff fl32(inter/den) > 0.7f  <=>  inter >= M*den exactly (M = RNE boundary)
    const double MTHR = (double)0.7f + 0x1p-25;

    auto scanNext = [&](u32 from) -> u32 {    // first not-confirmed-dead chunk >= from
        for (u32 k = from >> 5; k < 3u; ++k) {
            u32 v = ~__hip_atomic_load(&bmL[k], __ATOMIC_RELAXED, __HIP_MEMORY_SCOPE_WORKGROUP);
            if (k == (from >> 5)) v &= ~((1u << (from & 31u)) - 1u);
            if (v) return k*32u + (u32)__builtin_ctz(v);
        }
        return 96u;
    };

    // exact-decision IoU apply (f32 fast path, rare f64 fallback), slot i vs box e
    #define APPLY(i, e, sA)  do {                                              \
        float yy1 = fmaxf((e).x, ry1[i]);                                      \
        float xx1 = fmaxf((e).y, rx1[i]);                                      \
        float yy2 = fminf((e).z, ry2[i]);                                      \
        float xx2 = fminf((e).w, rx2[i]);                                      \
        float inter = fmaxf(yy2 - yy1, 0.f) * fmaxf(xx2 - xx1, 0.f);           \
        float den = (((sA) + rA[i]) - inter) + 1e-9f;   /* exact ref order */  \
        bool sup = inter >= 0.700001f * den;                                   \
        bool amb = (!sup) && (inter >= 0.699999f * den);                       \
        if (__any((int)amb)) sup = ((double)inter >= MTHR * (double)den);      \
        if (sup) mask &= ~(1u << (i));                                         \
    } while (0)

    // ---------- torch-passing lazy producer/consumer greedy NMS ----------
    for (int g = 0; g < GUARD_MAX; ++g) {
        u32 pv = __hip_atomic_load(ctrlP, __ATOMIC_ACQUIRE, __HIP_MEMORY_SCOPE_WORKGROUP);
        if (pv & DONEBIT) break;
        u32 cnt = (u32)__builtin_amdgcn_readfirstlane((int)(pv & CNTMASK));
        u32 f = __hip_atomic_load(ctrlF, __ATOMIC_ACQUIRE, __HIP_MEMORY_SCOPE_WORKGROUP);
        f = (u32)__builtin_amdgcn_readfirstlane((int)f);
        bool did = false;

        // ---- horizon membership: consume only chunks <= f+HOR ----
        u32 hm = 0;
        #pragma unroll
        for (int i = 0; i < NSLOT; ++i) {
            u32 s = (u32)i*8u + w;
            if (((slotAlive >> i) & 1u) && s <= f + HOR) hm |= 1u << i;
        }

        if (hm) {
            // align stragglers (fresh horizon entrants) up to cmax
            u32 cmax = 0;
            #pragma unroll
            for (int i = 0; i < NSLOT; ++i)
                if ((hm >> i) & 1u) cmax = max(cmax, consS[i]);
            #pragma unroll
            for (int i = 0; i < NSLOT; ++i) {
                if (((hm >> i) & 1u) && consS[i] < cmax) {
                    for (u32 q = consS[i]; q < cmax; ++q) {
                        float4 e = ringL[q];
                        float sA = (e.z - e.x) * (e.w - e.y);
                        APPLY(i, e, sA);
                    }
                    consS[i] = cmax;
                    did = true;
                }
            }
            // shared stream [cmax, cnt) applied to every horizon slot
            if (cmax < cnt) {
                float4 e = ringL[cmax];
                for (u32 q = cmax; q < cnt; ++q) {
                    float4 en = e;
                    if (q + 1 < cnt) en = ringL[q + 1];        // prefetch
                    float sA = (e.z - e.x) * (e.w - e.y);
                    #pragma unroll
                    for (int i = 0; i < NSLOT; ++i)
                        if ((hm >> i) & 1u) APPLY(i, e, sA);
                    e = en;
                }
                #pragma unroll
                for (int i = 0; i < NSLOT; ++i)
                    if ((hm >> i) & 1u) consS[i] = cnt;
                did = true;
            }
            if (did) {      // refresh aliveness of horizon slots; mark died chunks
                u32 na = slotAlive;
                #pragma unroll
                for (int i = 0; i < NSLOT; ++i)
                    if ((hm >> i) & 1u)
                        if (!__ballot((mask >> i) & 1u)) na &= ~(1u << i);
                u32 diedm = slotAlive & ~na;
                slotAlive = na;
                if (diedm && lane == 0) {
                    #pragma unroll
                    for (int i = 0; i < NSLOT; ++i)
                        if ((diedm >> i) & 1u) {
                            u32 s = (u32)i*8u + w;
                            __hip_atomic_fetch_or(&bmL[s >> 5], 1u << (s & 31u),
                                                  __ATOMIC_RELAXED, __HIP_MEMORY_SCOPE_WORKGROUP);
                        }
                }
            }
        }

        if ((f & 7u) == w && f < NCHUNK) {    // ---- torch points at one of my chunks ----
            u32 pv2 = __hip_atomic_load(ctrlP, __ATOMIC_ACQUIRE, __HIP_MEMORY_SCOPE_WORKGROUP);
            if (pv2 & DONEBIT) break;
            u32 cnt2 = pv2 & CNTMASK;
            if (cnt2 != cnt) continue;        // stale view: re-iterate, catch up first
            u32 fi = f >> 3;
            u32 cfi;
            switch (fi) {
                case 0:  cfi = consS[0];  break;
                case 1:  cfi = consS[1];  break;
                case 2:  cfi = consS[2];  break;
                case 3:  cfi = consS[3];  break;
                case 4:  cfi = consS[4];  break;
                case 5:  cfi = consS[5];  break;
                case 6:  cfi = consS[6];  break;
                case 7:  cfi = consS[7];  break;
                case 8:  cfi = consS[8];  break;
                case 9:  cfi = consS[9];  break;
                case 10: cfi = consS[10]; break;
                default: cfi = consS[11]; break;
            }
            if ((slotAlive >> fi) & 1u) {
                if (cfi != cnt2) continue;    // not yet caught up on my torch chunk
                // ---- become producer: hoist chunk fi into named regs (once/reign) ----
                float cy1, cx1, cy2, cx2, cA_;
                switch (fi) {
                    case 0:  cy1=ry1[0];  cx1=rx1[0];  cy2=ry2[0];  cx2=rx2[0];  cA_=rA[0];  break;
                    case 1:  cy1=ry1[1];  cx1=rx1[1];  cy2=ry2[1];  cx2=rx2[1];  cA_=rA[1];  break;
                    case 2:  cy1=ry1[2];  cx1=rx1[2];  cy2=ry2[2];  cx2=rx2[2];  cA_=rA[2];  break;
                    case 3:  cy1=ry1[3];  cx1=rx1[3];  cy2=ry2[3];  cx2=rx2[3];  cA_=rA[3];  break;
                    case 4:  cy1=ry1[4];  cx1=rx1[4];  cy2=ry2[4];  cx2=rx2[4];  cA_=rA[4];  break;
                    case 5:  cy1=ry1[5];  cx1=rx1[5];  cy2=ry2[5];  cx2=rx2[5];  cA_=rA[5];  break;
                    case 6:  cy1=ry1[6];  cx1=rx1[6];  cy2=ry2[6];  cx2=rx2[6];  cA_=rA[6];  break;
                    case 7:  cy1=ry1[7];  cx1=rx1[7];  cy2=ry2[7];  cx2=rx2[7];  cA_=rA[7];  break;
                    case 8:  cy1=ry1[8];  cx1=rx1[8];  cy2=ry2[8];  cx2=rx2[8];  cA_=rA[8];  break;
                    case 9:  cy1=ry1[9];  cx1=rx1[9];  cy2=ry2[9];  cx2=rx2[9];  cA_=rA[9];  break;
                    case 10: cy1=ry1[10]; cx1=rx1[10]; cy2=ry2[10]; cx2=rx2[10]; cA_=rA[10]; break;
                    default: cy1=ry1[11]; cx1=rx1[11]; cy2=ry2[11]; cx2=rx2[11]; cA_=rA[11]; break;
                }
                u64 am = __ballot((mask >> fi) & 1u);   // chunk alive mask (SGPR)
                mask &= ~(1u << fi);                    // chunk retires with the reign
                slotAlive &= ~(1u << fi);
                u32 pc = cnt2;
                bool alldone = false;
                __builtin_amdgcn_s_setprio(1);
                while (true) {
                    if (!am) {                          // chunk exhausted -> pass torch
                        if (lane == 0)
                            __hip_atomic_fetch_or(&bmL[f >> 5], 1u << (f & 31u),
                                                  __ATOMIC_RELAXED, __HIP_MEMORY_SCOPE_WORKGROUP);
                        u32 nxt = scanNext(f + 1u);
                        if (nxt >= NCHUNK) {
                            if (lane == 0)
                                __hip_atomic_store(ctrlP, pc | DONEBIT, __ATOMIC_RELEASE,
                                                   __HIP_MEMORY_SCOPE_WORKGROUP);
                            alldone = true;
                        } else if (lane == 0) {
                            __hip_atomic_store(ctrlF, nxt, __ATOMIC_RELEASE,
                                               __HIP_MEMORY_SCOPE_WORKGROUP);
                        }
                        break;
                    }
                    u32 ol = (u32)__builtin_ctzll(am);   // first alive lane = next pick
                    float sy1 = __uint_as_float((u32)__builtin_amdgcn_readlane((int)__float_as_uint(cy1), (int)ol));
                    float sx1 = __uint_as_float((u32)__builtin_amdgcn_readlane((int)__float_as_uint(cx1), (int)ol));
                    float sy2 = __uint_as_float((u32)__builtin_amdgcn_readlane((int)__float_as_uint(cy2), (int)ol));
                    float sx2 = __uint_as_float((u32)__builtin_amdgcn_readlane((int)__float_as_uint(cx2), (int)ol));
                    if (lane == ol) {
                        ppL[f*64u + ol] = (u16)pc;
                        ringL[pc] = make_float4(cy1, cx1, cy2, cx2);
                    }
                    float sA = (sy2 - sy1) * (sx2 - sx1);   // bit-exact area recompute
                    float yy1 = fmaxf(sy1, cy1);
                    float xx1 = fmaxf(sx1, cx1);
                    float yy2 = fminf(sy2, cy2);
                    float xx2 = fminf(sx2, cx2);
                    float inter = fmaxf(yy2 - yy1, 0.f) * fmaxf(xx2 - xx1, 0.f);
                    float den = ((sA + cA_) - inter) + 1e-9f;
                    u64 supp = __ballot((double)inter >= MTHR * (double)den);
                    am &= ~supp;                            // pick suppresses itself too
                    ++pc;
                    u32 val = pc | ((pc >= POST) ? DONEBIT : 0u);
                    if (lane == 0)                          // release drains ring write
                        __hip_atomic_store(ctrlP, val, __ATOMIC_RELEASE,
                                           __HIP_MEMORY_SCOPE_WORKGROUP);
                    if (pc >= POST) { alldone = true; break; }
                }
                __builtin_amdgcn_s_setprio(0);
                if (alldone) break;
                continue;                        // back to consumer (my other chunks lag)
            } else {
                // my torch chunk is dead -> relay torch onward
                if (lane == 0)
                    __hip_atomic_fetch_or(&bmL[f >> 5], 1u << (f & 31u),
                                          __ATOMIC_RELAXED, __HIP_MEMORY_SCOPE_WORKGROUP);
                u32 nxt = scanNext(f + 1u);
                if (nxt >= NCHUNK) {
                    if (lane == 0)
                        __hip_atomic_store(ctrlP, cnt2 | DONEBIT, __ATOMIC_RELEASE,
                                           __HIP_MEMORY_SCOPE_WORKGROUP);
                    break;
                }
                if (lane == 0)
                    __hip_atomic_store(ctrlF, nxt, __ATOMIC_RELEASE,
                                       __HIP_MEMORY_SCOPE_WORKGROUP);
                continue;
            }
        }
        if (!did) __builtin_amdgcn_s_sleep(1);
    }
    __syncthreads();
    u32 pend = (*ctrlP) & CNTMASK;

    // ---------- epilogue: deferred output writes ----------
    const size_t sbase = (size_t)BATCH * POST * 4;
    #pragma unroll
    for (int i = 0; i < NSLOT; ++i) {
        u32 s = (u32)i*8u + w;
        u32 r = s*64u + lane;
        if (s < NCHUNK && r < TOPN) {
            u32 v = (u32)ppL[r];
            if (v != 0xFFFFu) {
                size_t row = (size_t)b * POST + v;
                float* ob = out + row * 4;
                ob[0] = fminf(fmaxf(ry1[i], 0.f), 1.f);
                ob[1] = fminf(fmaxf(rx1[i], 0.f), 1.f);
                ob[2] = fminf(fmaxf(ry2[i], 0.f), 1.f);
                ob[3] = fminf(fmaxf(rx2[i], 0.f), 1.f);
                out[sbase + row] = __uint_as_float((u32)(keysL[r] >> 32));
            }
        }
    }
    for (int p = (int)pend + tid; p < POST; p += NT) {
        size_t row = (size_t)b * POST + p;
        float* ob = out + row * 4;
        ob[0]=0.f; ob[1]=0.f; ob[2]=0.f; ob[3]=0.f;
        out[sbase + row] = 0.f;
    }
    #undef APPLY
}

extern "C" void kernel_launch(void* const* d_in, const int* in_sizes, int n_in,
                              void* d_out, int out_size, void* d_ws, size_t ws_size,
                              hipStream_t stream) {
    const float* deltas  = (const float*)d_in[0];  // [64,31,31,36] f32
    const float* probs   = (const float*)d_in[1];  // [64,31,31,9]  f32
    // d_in[2] = gt_labels (unused)
    const float* anchors = (const float*)d_in[3];  // [8649,4] f32
    float* out = (float*)d_out;                    // 480000 f32

    roibbox_kernel<<<dim3(BATCH), dim3(NT), 0, stream>>>(deltas, probs, anchors, out);
}

// Round 6
// 1269.157 us; speedup vs baseline: 1.7850x; 1.7850x over previous
//
#include <hip/hip_runtime.h>
#include <math.h>

typedef unsigned int u32;
typedef unsigned short u16;
typedef unsigned long long u64;

#define BATCH 64
#define A_TOT 8649
#define TOPN  6000
#define POST  1500
#define NB    4096
#define NT    512
#define NWAVE 8
#define NSLOT 12
#define NCHUNK 94          // ceil(6000/64): chunk s holds ranks [s*64, s*64+64)
#define HOR   16u          // lazy horizon: admit chunk s when torch f >= s-HOR
#define ENTSTEP 64u        // entrant catch-up picks per background visit
#define DONEBIT 0x80000000u
#define CNTMASK 0x7FFFFFFFu
#define GUARD_MAX (1 << 18)

// LDS layout (bytes); overlapping regions have disjoint lifetimes:
//   [0,      69192)  keys    u64[8649]   ([0,48000) live to the end: scores)
//   [69632,  86016)  bucketA u32[4096]   (sort only)
//   [86016, 102400)  bucketB u32[4096]   (sort only)
//   [102400,106496)  stemp   u32[1024]   (scan only)
//   [69632,  93632)  ring    float4[1500] (NMS; overlaps dead buckets)
//   [93632, 105632)  pp      u16[6000]    (NMS/epilogue; overlaps dead bucketB)
//   [105632,105652)  ctrl: u32 prodcnt, u32 torch, u32 bm[3] (overlaps dead stemp)
#define LDS_BYTES 106496

__global__ __launch_bounds__(NT, 2) void roibbox_kernel(
    const float* __restrict__ deltas,    // [B, A, 4]
    const float* __restrict__ probs,     // [B, A]
    const float* __restrict__ anchors,   // [A, 4]
    float* __restrict__ out)             // [B*POST*4] boxes then [B*POST] scores
{
    #pragma clang fp contract(off)
    __shared__ alignas(16) char smem[LDS_BYTES];
    u64*    keysL   = (u64*)   (smem + 0);
    u32*    bucketA = (u32*)   (smem + 69632);
    u32*    bucketB = (u32*)   (smem + 86016);
    u32*    stemp   = (u32*)   (smem + 102400);
    float4* ringL   = (float4*)(smem + 69632);
    u16*    ppL     = (u16*)   (smem + 93632);
    u32*    ctrlP   = (u32*)   (smem + 105632);   // produced count | DONEBIT
    u32*    ctrlF   = (u32*)   (smem + 105636);   // torch: frontier chunk index
    u32*    bmL     = (u32*)   (smem + 105640);   // [3] confirmed-dead chunk bitmap

    const int tid = threadIdx.x;
    const int b   = blockIdx.x;
    const u32 lane = (u32)tid & 63u;
    const u32 w    = (u32)tid >> 6;
    const float* pb = probs + (size_t)b * A_TOT;

    // ---------- init ----------
    #pragma unroll
    for (int i = 0; i < NB/NT; ++i) bucketA[tid + i*NT] = 0u;
    __syncthreads();

    // ---------- histogram (bucket by score; reversed so bucket 0 = highest) ----------
    for (int j = tid; j < A_TOT; j += NT) {
        float s = pb[j];
        int bkt = (int)(s * (float)NB);
        bkt = (NB-1) - min(max(bkt, 0), NB-1);
        atomicAdd(&bucketA[bkt], 1u);
    }
    __syncthreads();

    // ---------- exclusive scan over 4096 counts ----------
    {
        int base8 = tid << 3;
        u32 c[8]; u32 ms = 0;
        #pragma unroll
        for (int i = 0; i < 8; ++i) { c[i] = bucketA[base8+i]; ms += c[i]; }
        stemp[tid] = ms;
        __syncthreads();
        int src = 0;
        for (int off = 1; off < NT; off <<= 1) {
            u32 v = stemp[src*NT + tid];
            if (tid >= off) v += stemp[src*NT + tid - off];
            stemp[(src^1)*NT + tid] = v;
            __syncthreads();
            src ^= 1;
        }
        u32 excl = stemp[src*NT + tid] - ms;
        #pragma unroll
        for (int i = 0; i < 8; ++i) {
            bucketA[base8+i] = excl; bucketB[base8+i] = excl; excl += c[i];
        }
    }
    __syncthreads();

    // ---------- scatter keys into LDS ----------
    for (int j = tid; j < A_TOT; j += NT) {
        float s = pb[j];
        int bkt = (int)(s * (float)NB);
        bkt = (NB-1) - min(max(bkt, 0), NB-1);
        u32 pos = atomicAdd(&bucketB[bkt], 1u);
        keysL[pos] = ((u64)__float_as_uint(s) << 32) | (u64)(~(u32)j);
    }
    __syncthreads();

    // ---------- per-bucket insertion sort (descending; keys unique) ----------
    for (int bkt = tid; bkt < NB; bkt += NT) {
        int begin = (int)bucketA[bkt], end = (int)bucketB[bkt];
        for (int k = begin + 1; k < end; ++k) {
            u64 key = keysL[k];
            int m = k - 1;
            while (m >= begin && keysL[m] < key) { keysL[m+1] = keysL[m]; --m; }
            keysL[m+1] = key;
        }
    }
    __syncthreads();

    // ---------- decode, round-robin chunks: chunk s = i*8+w, rank = s*64+lane ----------
    float ry1[NSLOT], rx1[NSLOT], ry2[NSLOT], rx2[NSLOT], rA[NSLOT];
    u32 mask = 0;
    #pragma unroll
    for (int i = 0; i < NSLOT; ++i) {
        u32 s = (u32)i*8u + w;
        u32 r = s*64u + lane;
        ry1[i]=0.f; rx1[i]=0.f; ry2[i]=0.f; rx2[i]=0.f; rA[i]=0.f;
        if (s < NCHUNK && r < TOPN) {
            u64 k = keysL[r];
            u32 aidx = ~((u32)k);
            float4 av = *(const float4*)(anchors + (size_t)aidx * 4);
            float4 dv = *(const float4*)(deltas + ((size_t)b * A_TOT + aidx) * 4);
            float d0 = dv.x*0.1f, d1 = dv.y*0.1f, d2 = dv.z*0.2f, d3 = dv.w*0.2f;
            float ah = av.z - av.x, aw = av.w - av.y;
            float acy = av.x + 0.5f*ah, acx = av.y + 0.5f*aw;
            float h  = (float)exp((double)d2) * ah;   // correctly-rounded fp32 exp
            float wd = (float)exp((double)d3) * aw;
            float cy = d0*ah + acy;                   // contract(off): mul then add
            float cx = d1*aw + acx;
            ry1[i] = cy - 0.5f*h;  rx1[i] = cx - 0.5f*wd;
            ry2[i] = cy + 0.5f*h;  rx2[i] = cx + 0.5f*wd;
            rA[i]  = (ry2[i]-ry1[i])*(rx2[i]-rx1[i]);
            mask |= 1u << i;
        }
    }

    for (int j = tid; j < TOPN/2; j += NT) ((u32*)ppL)[j] = 0xFFFFFFFFu;
    if (tid == 0) { *ctrlP = 0u; *ctrlF = 0u; bmL[0] = 0u; bmL[1] = 0u; bmL[2] = 0xC0000000u; }
    __syncthreads();

    // suppress iff fl32(inter/den) > 0.7f  <=>  inter >= M*den exactly (M = RNE boundary)
    const double MTHR = (double)0.7f + 0x1p-25;

    auto scanNext = [&](u32 from) -> u32 {    // first not-confirmed-dead chunk >= from
        for (u32 k = from >> 5; k < 3u; ++k) {
            u32 v = ~__hip_atomic_load(&bmL[k], __ATOMIC_RELAXED, __HIP_MEMORY_SCOPE_WORKGROUP);
            if (k == (from >> 5)) v &= ~((1u << (from & 31u)) - 1u);
            if (v) return k*32u + (u32)__builtin_ctz(v);
        }
        return 96u;
    };

    #define APPLY(i, e, sA)  do {                                              \
        float yy1 = fmaxf((e).x, ry1[i]);                                      \
        float xx1 = fmaxf((e).y, rx1[i]);                                      \
        float yy2 = fminf((e).z, ry2[i]);                                      \
        float xx2 = fminf((e).w, rx2[i]);                                      \
        float inter = fmaxf(yy2 - yy1, 0.f) * fmaxf(xx2 - xx1, 0.f);           \
        float den = (((sA) + rA[i]) - inter) + 1e-9f;   /* exact ref order */  \
        if ((double)inter >= MTHR * (double)den) mask &= ~(1u << (i));         \
    } while (0)

    // pipelined fixed-slot catch-up of entrant over picks [entC, tgt)
    #define ENTRUN(I, tgt) do {                                                \
        u32 q_ = entC;                                                         \
        if (q_ < (tgt)) {                                                      \
            float4 e0_ = ringL[q_];                                            \
            float4 e1_ = (q_+1 < (tgt)) ? ringL[q_+1] : e0_;                   \
            for (; q_ < (tgt); ++q_) {                                         \
                float4 e_ = e0_; e0_ = e1_;                                    \
                if (q_+2 < (tgt)) e1_ = ringL[q_+2];                           \
                float sA_ = (e_.z - e_.x) * (e_.w - e_.y);                     \
                APPLY(I, e_, sA_);                                             \
            }                                                                  \
            entC = (tgt);                                                      \
        }                                                                      \
    } while (0)

    // ---------- NMS state ----------
    u32 hmask = 0;          // slots in caught-up horizon group (wave-uniform)
    u32 consumed = 0;       // group pick counter
    u32 hnext = 0;          // next slot index to admit
    u32 entSlot = NSLOT;    // active entrant slot (NSLOT = none)
    u32 entC = 0;           // entrant pick counter

    auto ent_step = [&](u32 tgt) {
        switch (entSlot) {
            case 0:  ENTRUN(0,  tgt); break;
            case 1:  ENTRUN(1,  tgt); break;
            case 2:  ENTRUN(2,  tgt); break;
            case 3:  ENTRUN(3,  tgt); break;
            case 4:  ENTRUN(4,  tgt); break;
            case 5:  ENTRUN(5,  tgt); break;
            case 6:  ENTRUN(6,  tgt); break;
            case 7:  ENTRUN(7,  tgt); break;
            case 8:  ENTRUN(8,  tgt); break;
            case 9:  ENTRUN(9,  tgt); break;
            case 10: ENTRUN(10, tgt); break;
            default: ENTRUN(11, tgt); break;
        }
    };
    auto ent_promote = [&]() {        // call only when entC == consumed
        u32 es = entSlot;
        if (__ballot((mask >> es) & 1u)) hmask |= 1u << es;
        else if (lane == 0) {
            u32 s = es*8u + w;
            __hip_atomic_fetch_or(&bmL[s >> 5], 1u << (s & 31u),
                                  __ATOMIC_RELAXED, __HIP_MEMORY_SCOPE_WORKGROUP);
        }
        entSlot = NSLOT;
    };
    auto group_consume = [&](u32 cnt) {
        if (consumed >= cnt) return;
        if (hmask) {
            u32 q = consumed;
            float4 e0 = ringL[q];
            float4 e1 = (q+1 < cnt) ? ringL[q+1] : e0;
            for (; q < cnt; ++q) {
                float4 e = e0; e0 = e1;
                if (q+2 < cnt) e1 = ringL[q+2];
                float sA = (e.z - e.x) * (e.w - e.y);
                #pragma unroll
                for (int i = 0; i < NSLOT; ++i)
                    if ((hmask >> i) & 1u) APPLY(i, e, sA);
            }
            u32 nh = hmask;
            #pragma unroll
            for (int i = 0; i < NSLOT; ++i)
                if ((hmask >> i) & 1u)
                    if (!__ballot((mask >> i) & 1u)) nh &= ~(1u << i);
            u32 diedm = hmask & ~nh;
            hmask = nh;
            if (diedm && lane == 0) {
                #pragma unroll
                for (int i = 0; i < NSLOT; ++i)
                    if ((diedm >> i) & 1u) {
                        u32 s = (u32)i*8u + w;
                        __hip_atomic_fetch_or(&bmL[s >> 5], 1u << (s & 31u),
                                              __ATOMIC_RELAXED, __HIP_MEMORY_SCOPE_WORKGROUP);
                    }
            }
        }
        consumed = cnt;
    };

    // ---------- torch-passing lazy producer/consumer greedy NMS ----------
    for (int g = 0; g < GUARD_MAX; ++g) {
        u32 pv = __hip_atomic_load(ctrlP, __ATOMIC_ACQUIRE, __HIP_MEMORY_SCOPE_WORKGROUP);
        if (pv & DONEBIT) break;
        u32 cnt = pv & CNTMASK;
        u32 f = __hip_atomic_load(ctrlF, __ATOMIC_ACQUIRE, __HIP_MEMORY_SCOPE_WORKGROUP);

        if ((f & 7u) == w && f < NCHUNK) {
            // ---- torch at my chunk: full-priority service ----
            u32 pv2 = __hip_atomic_load(ctrlP, __ATOMIC_ACQUIRE, __HIP_MEMORY_SCOPE_WORKGROUP);
            if (pv2 & DONEBIT) break;
            u32 cnt2 = pv2 & CNTMASK;      // final until I produce (only torch produces)
            group_consume(cnt2);
            u32 fi = f >> 3;               // slot index of chunk f on this wave
            if (entSlot < NSLOT && entSlot <= fi) { ent_step(consumed); ent_promote(); }
            if (hnext <= fi) {             // force-admit everything up to fi
                u32 svS = entSlot, svC = entC;
                while (hnext <= fi) {
                    entSlot = hnext++; entC = 0;
                    ent_step(consumed); ent_promote();
                }
                entSlot = svS; entC = svC;
            }
            if ((hmask >> fi) & 1u) {
                // ---- produce: hoist chunk fi into named regs (once/reign) ----
                float cy1, cx1, cy2, cx2, cA_;
                switch (fi) {
                    case 0:  cy1=ry1[0];  cx1=rx1[0];  cy2=ry2[0];  cx2=rx2[0];  cA_=rA[0];  break;
                    case 1:  cy1=ry1[1];  cx1=rx1[1];  cy2=ry2[1];  cx2=rx2[1];  cA_=rA[1];  break;
                    case 2:  cy1=ry1[2];  cx1=rx1[2];  cy2=ry2[2];  cx2=rx2[2];  cA_=rA[2];  break;
                    case 3:  cy1=ry1[3];  cx1=rx1[3];  cy2=ry2[3];  cx2=rx2[3];  cA_=rA[3];  break;
                    case 4:  cy1=ry1[4];  cx1=rx1[4];  cy2=ry2[4];  cx2=rx2[4];  cA_=rA[4];  break;
                    case 5:  cy1=ry1[5];  cx1=rx1[5];  cy2=ry2[5];  cx2=rx2[5];  cA_=rA[5];  break;
                    case 6:  cy1=ry1[6];  cx1=rx1[6];  cy2=ry2[6];  cx2=rx2[6];  cA_=rA[6];  break;
                    case 7:  cy1=ry1[7];  cx1=rx1[7];  cy2=ry2[7];  cx2=rx2[7];  cA_=rA[7];  break;
                    case 8:  cy1=ry1[8];  cx1=rx1[8];  cy2=ry2[8];  cx2=rx2[8];  cA_=rA[8];  break;
                    case 9:  cy1=ry1[9];  cx1=rx1[9];  cy2=ry2[9];  cx2=rx2[9];  cA_=rA[9];  break;
                    case 10: cy1=ry1[10]; cx1=rx1[10]; cy2=ry2[10]; cx2=rx2[10]; cA_=rA[10]; break;
                    default: cy1=ry1[11]; cx1=rx1[11]; cy2=ry2[11]; cx2=rx2[11]; cA_=rA[11]; break;
                }
                u64 am = __ballot((mask >> fi) & 1u);   // chunk alive mask (SGPR)
                mask &= ~(1u << fi);                    // chunk retires with the reign
                hmask &= ~(1u << fi);
                u32 pc = cnt2;
                bool alldone = false;
                __builtin_amdgcn_s_setprio(1);
                while (true) {
                    if (!am) {                          // chunk exhausted -> pass torch
                        if (lane == 0)
                            __hip_atomic_fetch_or(&bmL[f >> 5], 1u << (f & 31u),
                                                  __ATOMIC_RELAXED, __HIP_MEMORY_SCOPE_WORKGROUP);
                        u32 nxt = scanNext(f + 1u);
                        if (nxt >= NCHUNK) {
                            if (lane == 0)
                                __hip_atomic_store(ctrlP, pc | DONEBIT, __ATOMIC_RELEASE,
                                                   __HIP_MEMORY_SCOPE_WORKGROUP);
                            alldone = true;
                        } else if (lane == 0) {
                            __hip_atomic_store(ctrlF, nxt, __ATOMIC_RELEASE,
                                               __HIP_MEMORY_SCOPE_WORKGROUP);
                        }
                        break;
                    }
                    u32 ol = (u32)__builtin_ctzll(am);   // first alive lane = next pick
                    float sy1 = __uint_as_float((u32)__builtin_amdgcn_readlane((int)__float_as_uint(cy1), (int)ol));
                    float sx1 = __uint_as_float((u32)__builtin_amdgcn_readlane((int)__float_as_uint(cx1), (int)ol));
                    float sy2 = __uint_as_float((u32)__builtin_amdgcn_readlane((int)__float_as_uint(cy2), (int)ol));
                    float sx2 = __uint_as_float((u32)__builtin_amdgcn_readlane((int)__float_as_uint(cx2), (int)ol));
                    if (lane == ol) {
                        ppL[f*64u + ol] = (u16)pc;
                        ringL[pc] = make_float4(cy1, cx1, cy2, cx2);
                    }
                    float sA = (sy2 - sy1) * (sx2 - sx1);   // bit-exact area recompute
                    float yy1 = fmaxf(sy1, cy1);
                    float xx1 = fmaxf(sx1, cx1);
                    float yy2 = fminf(sy2, cy2);
                    float xx2 = fminf(sx2, cx2);
                    float inter = fmaxf(yy2 - yy1, 0.f) * fmaxf(xx2 - xx1, 0.f);
                    float den = ((sA + cA_) - inter) + 1e-9f;
                    u64 supp = __ballot((double)inter >= MTHR * (double)den);
                    am &= ~supp;                            // pick suppresses itself too
                    ++pc;
                    u32 val = pc | ((pc >= POST) ? DONEBIT : 0u);
                    if (lane == 0)                          // release drains ring write
                        __hip_atomic_store(ctrlP, val, __ATOMIC_RELEASE,
                                           __HIP_MEMORY_SCOPE_WORKGROUP);
                    if (pc >= POST) { alldone = true; break; }
                }
                __builtin_amdgcn_s_setprio(0);
                // NOTE: consumed stays at cnt2 — my other hmask slots still need
                // picks [cnt2, pc) applied; group_consume handles it next iteration.
                if (alldone) break;
                continue;
            } else {
                // my torch chunk is dead (bmL already marked) -> relay torch onward
                u32 nxt = scanNext(f + 1u);
                if (nxt >= NCHUNK) {
                    if (lane == 0)
                        __hip_atomic_store(ctrlP, cnt2 | DONEBIT, __ATOMIC_RELEASE,
                                           __HIP_MEMORY_SCOPE_WORKGROUP);
                    break;
                }
                if (lane == 0)
                    __hip_atomic_store(ctrlF, nxt, __ATOMIC_RELEASE,
                                       __HIP_MEMORY_SCOPE_WORKGROUP);
                continue;
            }
        }

        // ---- background: group backlog, entrant progress, admission ----
        bool idle = true;
        if (cnt > consumed) { group_consume(cnt); idle = false; }
        if (entSlot < NSLOT) {
            if (entC < consumed) {
                u32 tgt = consumed; u32 lim = entC + ENTSTEP;
                if (lim < tgt) tgt = lim;
                ent_step(tgt);
                idle = false;
            }
            if (entC == consumed) ent_promote();
        } else if (hnext < NSLOT) {
            u32 s = (u32)hnext*8u + w;
            if (s >= NCHUNK) hnext = NSLOT;
            else if (s <= f + HOR) {
                entSlot = hnext++; entC = 0;
                if (entC == consumed) ent_promote();
                idle = false;
            }
        }
        if (idle) __builtin_amdgcn_s_sleep(2);
    }
    __syncthreads();
    u32 pend = (*ctrlP) & CNTMASK;

    // ---------- epilogue: deferred output writes ----------
    const size_t sbase = (size_t)BATCH * POST * 4;
    #pragma unroll
    for (int i = 0; i < NSLOT; ++i) {
        u32 s = (u32)i*8u + w;
        u32 r = s*64u + lane;
        if (s < NCHUNK && r < TOPN) {
            u32 v = (u32)ppL[r];
            if (v != 0xFFFFu) {
                size_t row = (size_t)b * POST + v;
                float* ob = out + row * 4;
                ob[0] = fminf(fmaxf(ry1[i], 0.f), 1.f);
                ob[1] = fminf(fmaxf(rx1[i], 0.f), 1.f);
                ob[2] = fminf(fmaxf(ry2[i], 0.f), 1.f);
                ob[3] = fminf(fmaxf(rx2[i], 0.f), 1.f);
                out[sbase + row] = __uint_as_float((u32)(keysL[r] >> 32));
            }
        }
    }
    for (int p = (int)pend + tid; p < POST; p += NT) {
        size_t row = (size_t)b * POST + p;
        float* ob = out + row * 4;
        ob[0]=0.f; ob[1]=0.f; ob[2]=0.f; ob[3]=0.f;
        out[sbase + row] = 0.f;
    }
    #undef APPLY
    #undef ENTRUN
}

extern "C" void kernel_launch(void* const* d_in, const int* in_sizes, int n_in,
                              void* d_out, int out_size, void* d_ws, size_t ws_size,
                              hipStream_t stream) {
    const float* deltas  = (const float*)d_in[0];  // [64,31,31,36] f32
    const float* probs   = (const float*)d_in[1];  // [64,31,31,9]  f32
    // d_in[2] = gt_labels (unused)
    const float* anchors = (const float*)d_in[3];  // [8649,4] f32
    float* out = (float*)d_out;                    // 480000 f32

    roibbox_kernel<<<dim3(BATCH), dim3(NT), 0, stream>>>(deltas, probs, anchors, out);
}